// Round 1
// baseline (3410.237 us; speedup 1.0000x reference)
//
#include <hip/hip_runtime.h>
#include <hip/hip_bf16.h>
#include <math.h>

#define N_NODES 50000
#define N_EDGES 1600000
#define F_INF 3
#define H 64
#define G_GRAPHS 512
#define C_CLS 2
#define BN_EPS 1e-5f

// ---------------- scatter: agg[dst] += x[src], din=3 -----------------
__global__ void scatter3_kernel(const float* __restrict__ x,
                                const int* __restrict__ src,
                                const int* __restrict__ dst,
                                float* __restrict__ agg) {
    int e = blockIdx.x * blockDim.x + threadIdx.x;
    if (e >= N_EDGES) return;
    int s = src[e];
    int d = dst[e];
    float v0 = x[s * 3 + 0];
    float v1 = x[s * 3 + 1];
    float v2 = x[s * 3 + 2];
    atomicAdd(&agg[d * 3 + 0], v0);
    atomicAdd(&agg[d * 3 + 1], v1);
    atomicAdd(&agg[d * 3 + 2], v2);
}

// ---------------- scatter: agg[dst] += h[src], din=64 ----------------
// one thread per (edge, float4-group): 16 groups/edge
__global__ void scatter64_kernel(const float* __restrict__ h,
                                 const int* __restrict__ src,
                                 const int* __restrict__ dst,
                                 float* __restrict__ agg) {
    int tid = blockIdx.x * blockDim.x + threadIdx.x;
    if (tid >= N_EDGES * 16) return;
    int e = tid >> 4;
    int q = tid & 15;
    int s = src[e];
    int d = dst[e];
    float4 v = ((const float4*)(h + (size_t)s * H))[q];
    float* out = agg + (size_t)d * H + q * 4;
    atomicAdd(out + 0, v.x);
    atomicAdd(out + 1, v.y);
    atomicAdd(out + 2, v.z);
    atomicAdd(out + 3, v.w);
}

// ---------------- per-node MLP: relu(relu_bn((x+agg)@w1+b1)@w2+b2) ----
template <int DIN>
__global__ __launch_bounds__(256) void mlp_kernel(
    const float* __restrict__ xin, const float* __restrict__ agg,
    const float* __restrict__ w1, const float* __restrict__ b1,
    const float* __restrict__ bn_g, const float* __restrict__ bn_b,
    const float* __restrict__ bn_m, const float* __restrict__ bn_v,
    const float* __restrict__ w2, const float* __restrict__ b2,
    float* __restrict__ hout) {
    __shared__ float s_w1[DIN * H];
    __shared__ float s_w2[H * H];
    __shared__ float s_in[4][DIN];
    __shared__ float s_mid[4][H];
    __shared__ float s_scale[H], s_shift[H], s_b1[H], s_b2[H];

    int tid = threadIdx.x;
    for (int i = tid; i < DIN * H; i += 256) s_w1[i] = w1[i];
    for (int i = tid; i < H * H; i += 256) s_w2[i] = w2[i];
    if (tid < H) {
        float sc = rsqrtf(bn_v[tid] + BN_EPS) * bn_g[tid];
        s_scale[tid] = sc;
        s_shift[tid] = bn_b[tid] - bn_m[tid] * sc;
        s_b1[tid] = b1[tid];
        s_b2[tid] = b2[tid];
    }
    int ln = tid >> 6;   // 0..3 local node
    int j = tid & 63;    // output feature
    int node = blockIdx.x * 4 + ln;
    bool valid = node < N_NODES;
    if (valid) {
        if (DIN == 3) {
            if (j < 3) s_in[ln][j] = xin[node * 3 + j] + agg[node * 3 + j];
        } else {
            s_in[ln][j] = xin[(size_t)node * DIN + j] + agg[(size_t)node * DIN + j];
        }
    }
    __syncthreads();
    float acc = s_b1[j];
#pragma unroll
    for (int k = 0; k < DIN; k++) acc += s_in[ln][k] * s_w1[k * H + j];
    acc = acc * s_scale[j] + s_shift[j];
    acc = fmaxf(acc, 0.f);
    s_mid[ln][j] = acc;
    __syncthreads();
    float acc2 = s_b2[j];
#pragma unroll
    for (int k = 0; k < H; k++) acc2 += s_mid[ln][k] * s_w2[k * H + j];
    acc2 = fmaxf(acc2, 0.f);
    if (valid) hout[(size_t)node * H + j] = acc2;
}

// ---------------- pooling: pooled[batch[n]] += [h1|h2|h3][n] ---------
__global__ void pool_kernel(const float* __restrict__ h1,
                            const float* __restrict__ h2,
                            const float* __restrict__ h3,
                            const int* __restrict__ batch,
                            float* __restrict__ pooled) {
    int tid = blockIdx.x * blockDim.x + threadIdx.x;
    if (tid >= N_NODES * 48) return;
    int n = tid / 48;
    int q = tid - n * 48;       // 0..47
    int which = q >> 4;         // 0..2
    int fq = q & 15;            // float4 group
    const float* h = (which == 0) ? h1 : ((which == 1) ? h2 : h3);
    float4 v = ((const float4*)(h + (size_t)n * H))[fq];
    int g = batch[n];
    float* out = pooled + (size_t)g * (3 * H) + which * H + fq * 4;
    atomicAdd(out + 0, v.x);
    atomicAdd(out + 1, v.y);
    atomicAdd(out + 2, v.z);
    atomicAdd(out + 3, v.w);
}

// ---------------- head: relu(p@lin1+b) @ lin2 + b, log_softmax -------
__global__ __launch_bounds__(192) void final_kernel(
    const float* __restrict__ pooled, const float* __restrict__ lin1_w,
    const float* __restrict__ lin1_b, const float* __restrict__ lin2_w,
    const float* __restrict__ lin2_b, float* __restrict__ out) {
    __shared__ float row[3 * H];
    __shared__ float mid[3 * H];
    __shared__ float z[C_CLS];
    int g = blockIdx.x;
    int j = threadIdx.x;
    row[j] = pooled[(size_t)g * (3 * H) + j];
    __syncthreads();
    float acc = lin1_b[j];
    for (int k = 0; k < 3 * H; k++) acc += row[k] * lin1_w[k * (3 * H) + j];
    mid[j] = fmaxf(acc, 0.f);
    __syncthreads();
    if (j < C_CLS) {
        float zz = lin2_b[j];
        for (int k = 0; k < 3 * H; k++) zz += mid[k] * lin2_w[k * C_CLS + j];
        z[j] = zz;
    }
    __syncthreads();
    if (j < C_CLS) {
        float z0 = z[0], z1 = z[1];
        float m = fmaxf(z0, z1);
        float lse = m + logf(expf(z0 - m) + expf(z1 - m));
        out[g * C_CLS + j] = z[j];
        out[G_GRAPHS * C_CLS + g * C_CLS + j] = z[j] - lse;
    }
}

extern "C" void kernel_launch(void* const* d_in, const int* in_sizes, int n_in,
                              void* d_out, int out_size, void* d_ws, size_t ws_size,
                              hipStream_t stream) {
    const float* x = (const float*)d_in[0];
    // conv params: base index 1 + 8*layer
    const float* cw1[3], *cb1[3], *cg[3], *cbb[3], *cm[3], *cv[3], *cw2[3], *cb2[3];
    for (int l = 0; l < 3; l++) {
        int b = 1 + 8 * l;
        cw1[l] = (const float*)d_in[b + 0];
        cb1[l] = (const float*)d_in[b + 1];
        cg[l]  = (const float*)d_in[b + 2];
        cbb[l] = (const float*)d_in[b + 3];
        cm[l]  = (const float*)d_in[b + 4];
        cv[l]  = (const float*)d_in[b + 5];
        cw2[l] = (const float*)d_in[b + 6];
        cb2[l] = (const float*)d_in[b + 7];
    }
    const float* lin1_w = (const float*)d_in[25];
    const float* lin1_b = (const float*)d_in[26];
    const float* lin2_w = (const float*)d_in[27];
    const float* lin2_b = (const float*)d_in[28];
    const int* edge_index = (const int*)d_in[29];  // (2, E): row 0 = src, row 1 = dst
    const int* batch = (const int*)d_in[30];
    const int* src = edge_index;
    const int* dst = edge_index + N_EDGES;
    float* out = (float*)d_out;

    // workspace layout
    float* agg = (float*)d_ws;               // N*64
    float* h1 = agg + (size_t)N_NODES * H;   // N*64
    float* h2 = h1 + (size_t)N_NODES * H;
    float* h3 = h2 + (size_t)N_NODES * H;
    float* pooled = h3 + (size_t)N_NODES * H;  // G*192

    const int mlp_grid = (N_NODES + 3) / 4;
    const int sc64_grid = (N_EDGES * 16 + 255) / 256;

    // ---- layer 1 (din = 3) ----
    hipMemsetAsync(agg, 0, (size_t)N_NODES * 3 * sizeof(float), stream);
    scatter3_kernel<<<(N_EDGES + 255) / 256, 256, 0, stream>>>(x, src, dst, agg);
    mlp_kernel<3><<<mlp_grid, 256, 0, stream>>>(x, agg, cw1[0], cb1[0], cg[0], cbb[0],
                                                cm[0], cv[0], cw2[0], cb2[0], h1);
    // ---- layer 2 ----
    hipMemsetAsync(agg, 0, (size_t)N_NODES * H * sizeof(float), stream);
    scatter64_kernel<<<sc64_grid, 256, 0, stream>>>(h1, src, dst, agg);
    mlp_kernel<H><<<mlp_grid, 256, 0, stream>>>(h1, agg, cw1[1], cb1[1], cg[1], cbb[1],
                                                cm[1], cv[1], cw2[1], cb2[1], h2);
    // ---- layer 3 ----
    hipMemsetAsync(agg, 0, (size_t)N_NODES * H * sizeof(float), stream);
    scatter64_kernel<<<sc64_grid, 256, 0, stream>>>(h2, src, dst, agg);
    mlp_kernel<H><<<mlp_grid, 256, 0, stream>>>(h2, agg, cw1[2], cb1[2], cg[2], cbb[2],
                                                cm[2], cv[2], cw2[2], cb2[2], h3);
    // ---- pooling ----
    hipMemsetAsync(pooled, 0, (size_t)G_GRAPHS * 3 * H * sizeof(float), stream);
    pool_kernel<<<(N_NODES * 48 + 255) / 256, 256, 0, stream>>>(h1, h2, h3, batch, pooled);
    // ---- head ----
    final_kernel<<<G_GRAPHS, 3 * H, 0, stream>>>(pooled, lin1_w, lin1_b, lin2_w, lin2_b, out);
}

// Round 2
// 665.005 us; speedup vs baseline: 5.1281x; 5.1281x over previous
//
#include <hip/hip_runtime.h>
#include <hip/hip_bf16.h>
#include <math.h>

#define N_NODES 50000
#define N_EDGES 1600000
#define H 64
#define G_GRAPHS 512
#define C_CLS 2
#define BN_EPS 1e-5f

#define SCAN_CHUNK 1024            // elements per scan block (256 thr x 4)
#define SCAN_BLOCKS ((N_NODES + SCAN_CHUNK - 1) / SCAN_CHUNK)   // 49

// ---------- CSR build: histogram of dst ----------
__global__ void hist_kernel(const int* __restrict__ dst, int* __restrict__ count) {
    int e = blockIdx.x * blockDim.x + threadIdx.x;
    if (e < N_EDGES) atomicAdd(&count[dst[e]], 1);
}

// ---------- scan pass 1: per-block sums ----------
__global__ __launch_bounds__(256) void scan_sums_kernel(const int* __restrict__ count,
                                                        int* __restrict__ block_sums) {
    __shared__ int s[256];
    int base = blockIdx.x * SCAN_CHUNK + threadIdx.x * 4;
    int sum = 0;
#pragma unroll
    for (int i = 0; i < 4; i++) {
        int idx = base + i;
        if (idx < N_NODES) sum += count[idx];
    }
    s[threadIdx.x] = sum;
    __syncthreads();
    for (int off = 128; off > 0; off >>= 1) {
        if (threadIdx.x < off) s[threadIdx.x] += s[threadIdx.x + off];
        __syncthreads();
    }
    if (threadIdx.x == 0) block_sums[blockIdx.x] = s[0];
}

// ---------- scan pass 2: exclusive scan of block sums (small) ----------
__global__ void scan_offsets_kernel(int* __restrict__ block_sums, int* __restrict__ row_start) {
    if (threadIdx.x == 0 && blockIdx.x == 0) {
        int acc = 0;
        for (int i = 0; i < SCAN_BLOCKS; i++) {
            int v = block_sums[i];
            block_sums[i] = acc;
            acc += v;
        }
        row_start[N_NODES] = N_EDGES;
    }
}

// ---------- scan pass 3: per-block exclusive scan ----------
__global__ __launch_bounds__(256) void scan_final_kernel(const int* __restrict__ count,
                                                         const int* __restrict__ block_sums,
                                                         int* __restrict__ row_start) {
    __shared__ int s[256];
    int base = blockIdx.x * SCAN_CHUNK + threadIdx.x * 4;
    int c[4], local[4];
    int sum = 0;
#pragma unroll
    for (int i = 0; i < 4; i++) {
        int idx = base + i;
        c[i] = (idx < N_NODES) ? count[idx] : 0;
        local[i] = sum;
        sum += c[i];
    }
    s[threadIdx.x] = sum;
    __syncthreads();
    // Hillis-Steele inclusive scan over 256
    for (int off = 1; off < 256; off <<= 1) {
        int v = 0;
        if (threadIdx.x >= off) v = s[threadIdx.x - off];
        __syncthreads();
        if (threadIdx.x >= off) s[threadIdx.x] += v;
        __syncthreads();
    }
    int tprefix = s[threadIdx.x] - sum;  // exclusive prefix of this thread
    int boff = block_sums[blockIdx.x];
#pragma unroll
    for (int i = 0; i < 4; i++) {
        int idx = base + i;
        if (idx < N_NODES) row_start[idx] = boff + tprefix + local[i];
    }
}

// ---------- CSR fill ----------
__global__ void fill_kernel(const int* __restrict__ src, const int* __restrict__ dst,
                            int* __restrict__ cursor, int* __restrict__ edge_src) {
    int e = blockIdx.x * blockDim.x + threadIdx.x;
    if (e >= N_EDGES) return;
    int d = dst[e];
    int pos = atomicAdd(&cursor[d], 1);
    edge_src[pos] = src[e];
}

// ---------- layer 1: gather(din=3) + MLP, one wave per node ----------
__global__ __launch_bounds__(256) void gin_layer3_kernel(
    const float* __restrict__ x, const int* __restrict__ row_start,
    const int* __restrict__ edge_src,
    const float* __restrict__ w1, const float* __restrict__ b1,
    const float* __restrict__ bn_g, const float* __restrict__ bn_b,
    const float* __restrict__ bn_m, const float* __restrict__ bn_v,
    const float* __restrict__ w2, const float* __restrict__ b2,
    float* __restrict__ hout) {
    __shared__ float s_w1[3 * H];
    __shared__ float s_w2[H * H];
    __shared__ float s_mid[4][H];
    __shared__ float s_scale[H], s_shift[H], s_b1[H], s_b2[H];

    int tid = threadIdx.x;
    for (int i = tid; i < 3 * H; i += 256) s_w1[i] = w1[i];
    for (int i = tid; i < H * H; i += 256) s_w2[i] = w2[i];
    if (tid < H) {
        float sc = rsqrtf(bn_v[tid] + BN_EPS) * bn_g[tid];
        s_scale[tid] = sc;
        s_shift[tid] = bn_b[tid] - bn_m[tid] * sc;
        s_b1[tid] = b1[tid];
        s_b2[tid] = b2[tid];
    }
    __syncthreads();

    int wave = tid >> 6;
    int j = tid & 63;
    int node = blockIdx.x * 4 + wave;   // grid sized so node < N always

    int rs = row_start[node], re = row_start[node + 1];
    float a0 = 0.f, a1 = 0.f, a2 = 0.f;
    for (int t = rs + j; t < re; t += 64) {
        int s = edge_src[t];
        a0 += x[s * 3 + 0];
        a1 += x[s * 3 + 1];
        a2 += x[s * 3 + 2];
    }
#pragma unroll
    for (int off = 32; off > 0; off >>= 1) {
        a0 += __shfl_xor(a0, off);
        a1 += __shfl_xor(a1, off);
        a2 += __shfl_xor(a2, off);
    }
    float in0 = a0 + x[node * 3 + 0];
    float in1 = a1 + x[node * 3 + 1];
    float in2 = a2 + x[node * 3 + 2];

    float m = s_b1[j] + in0 * s_w1[0 * H + j] + in1 * s_w1[1 * H + j] + in2 * s_w1[2 * H + j];
    m = m * s_scale[j] + s_shift[j];
    m = fmaxf(m, 0.f);
    s_mid[wave][j] = m;
    __syncthreads();
    float o = s_b2[j];
#pragma unroll
    for (int k = 0; k < H; k++) o += s_mid[wave][k] * s_w2[k * H + j];
    o = fmaxf(o, 0.f);
    hout[(size_t)node * H + j] = o;
}

// ---------- layers 2/3: gather(din=64) + MLP, one wave per node ----------
__global__ __launch_bounds__(256) void gin_layer64_kernel(
    const float* __restrict__ hin, const int* __restrict__ row_start,
    const int* __restrict__ edge_src,
    const float* __restrict__ w1, const float* __restrict__ b1,
    const float* __restrict__ bn_g, const float* __restrict__ bn_b,
    const float* __restrict__ bn_m, const float* __restrict__ bn_v,
    const float* __restrict__ w2, const float* __restrict__ b2,
    float* __restrict__ hout) {
    __shared__ float s_w1[H * H];
    __shared__ float s_w2[H * H];
    __shared__ float s_in[4][H];
    __shared__ float s_mid[4][H];
    __shared__ float s_scale[H], s_shift[H], s_b1[H], s_b2[H];

    int tid = threadIdx.x;
    for (int i = tid; i < H * H; i += 256) { s_w1[i] = w1[i]; s_w2[i] = w2[i]; }
    if (tid < H) {
        float sc = rsqrtf(bn_v[tid] + BN_EPS) * bn_g[tid];
        s_scale[tid] = sc;
        s_shift[tid] = bn_b[tid] - bn_m[tid] * sc;
        s_b1[tid] = b1[tid];
        s_b2[tid] = b2[tid];
    }
    __syncthreads();

    int wave = tid >> 6;
    int j = tid & 63;
    int node = blockIdx.x * 4 + wave;   // grid covers exactly N

    int rs = row_start[node], re = row_start[node + 1];
    float a0 = 0.f, a1 = 0.f, a2 = 0.f, a3 = 0.f;
    int t = rs;
    for (; t + 3 < re; t += 4) {
        int s0 = edge_src[t], s1 = edge_src[t + 1], s2 = edge_src[t + 2], s3 = edge_src[t + 3];
        a0 += hin[(size_t)s0 * H + j];
        a1 += hin[(size_t)s1 * H + j];
        a2 += hin[(size_t)s2 * H + j];
        a3 += hin[(size_t)s3 * H + j];
    }
    for (; t < re; t++) a0 += hin[(size_t)edge_src[t] * H + j];
    float in = (a0 + a1) + (a2 + a3) + hin[(size_t)node * H + j];
    s_in[wave][j] = in;
    __syncthreads();

    float m = s_b1[j];
#pragma unroll
    for (int k = 0; k < H; k++) m += s_in[wave][k] * s_w1[k * H + j];
    m = m * s_scale[j] + s_shift[j];
    m = fmaxf(m, 0.f);
    s_mid[wave][j] = m;
    __syncthreads();

    float o = s_b2[j];
#pragma unroll
    for (int k = 0; k < H; k++) o += s_mid[wave][k] * s_w2[k * H + j];
    o = fmaxf(o, 0.f);
    hout[(size_t)node * H + j] = o;
}

// ---------- pool (batch sorted -> range per graph) + head ----------
__global__ __launch_bounds__(192) void pool_head_kernel(
    const float* __restrict__ h1, const float* __restrict__ h2,
    const float* __restrict__ h3, const int* __restrict__ batch,
    const float* __restrict__ lin1_w, const float* __restrict__ lin1_b,
    const float* __restrict__ lin2_w, const float* __restrict__ lin2_b,
    float* __restrict__ out) {
    __shared__ float s_row[3 * H];
    __shared__ float s_mid[3 * H];
    __shared__ float s_z[C_CLS];
    __shared__ int s_se[2];

    int g = blockIdx.x;
    int j = threadIdx.x;
    if (j < 2) {
        int target = g + j;
        int lo = 0, hi = N_NODES;
        while (lo < hi) {
            int mid = (lo + hi) >> 1;
            if (batch[mid] < target) lo = mid + 1; else hi = mid;
        }
        s_se[j] = lo;
    }
    __syncthreads();
    int ns = s_se[0], ne = s_se[1];

    int which = j >> 6;       // 0,1,2
    int f = j & 63;
    const float* h = (which == 0) ? h1 : ((which == 1) ? h2 : h3);
    float p = 0.f;
    for (int n = ns; n < ne; n++) p += h[(size_t)n * H + f];
    s_row[j] = p;
    __syncthreads();

    float acc = lin1_b[j];
    for (int k = 0; k < 3 * H; k++) acc += s_row[k] * lin1_w[k * (3 * H) + j];
    s_mid[j] = fmaxf(acc, 0.f);
    __syncthreads();

    if (j < C_CLS) {
        float z = lin2_b[j];
        for (int k = 0; k < 3 * H; k++) z += s_mid[k] * lin2_w[k * C_CLS + j];
        s_z[j] = z;
    }
    __syncthreads();
    if (j < C_CLS) {
        float z0 = s_z[0], z1 = s_z[1];
        float mx = fmaxf(z0, z1);
        float lse = mx + logf(expf(z0 - mx) + expf(z1 - mx));
        out[g * C_CLS + j] = s_z[j];
        out[G_GRAPHS * C_CLS + g * C_CLS + j] = s_z[j] - lse;
    }
}

extern "C" void kernel_launch(void* const* d_in, const int* in_sizes, int n_in,
                              void* d_out, int out_size, void* d_ws, size_t ws_size,
                              hipStream_t stream) {
    const float* x = (const float*)d_in[0];
    const float* cw1[3], *cb1[3], *cg[3], *cbb[3], *cm[3], *cv[3], *cw2[3], *cb2[3];
    for (int l = 0; l < 3; l++) {
        int b = 1 + 8 * l;
        cw1[l] = (const float*)d_in[b + 0];
        cb1[l] = (const float*)d_in[b + 1];
        cg[l]  = (const float*)d_in[b + 2];
        cbb[l] = (const float*)d_in[b + 3];
        cm[l]  = (const float*)d_in[b + 4];
        cv[l]  = (const float*)d_in[b + 5];
        cw2[l] = (const float*)d_in[b + 6];
        cb2[l] = (const float*)d_in[b + 7];
    }
    const float* lin1_w = (const float*)d_in[25];
    const float* lin1_b = (const float*)d_in[26];
    const float* lin2_w = (const float*)d_in[27];
    const float* lin2_b = (const float*)d_in[28];
    const int* edge_index = (const int*)d_in[29];
    const int* batch = (const int*)d_in[30];
    const int* src = edge_index;
    const int* dst = edge_index + N_EDGES;
    float* out = (float*)d_out;

    // workspace layout
    float* h1 = (float*)d_ws;                       // N*H
    float* h2 = h1 + (size_t)N_NODES * H;
    float* h3 = h2 + (size_t)N_NODES * H;
    int* edge_src = (int*)(h3 + (size_t)N_NODES * H);  // E
    int* count = edge_src + N_EDGES;                // N
    int* row_start = count + N_NODES;               // N+1
    int* cursor = row_start + N_NODES + 1;          // N
    int* block_sums = cursor + N_NODES;             // SCAN_BLOCKS

    // ---- build CSR (dst -> list of src) ----
    hipMemsetAsync(count, 0, N_NODES * sizeof(int), stream);
    hist_kernel<<<(N_EDGES + 255) / 256, 256, 0, stream>>>(dst, count);
    scan_sums_kernel<<<SCAN_BLOCKS, 256, 0, stream>>>(count, block_sums);
    scan_offsets_kernel<<<1, 64, 0, stream>>>(block_sums, row_start);
    scan_final_kernel<<<SCAN_BLOCKS, 256, 0, stream>>>(count, block_sums, row_start);
    hipMemcpyAsync(cursor, row_start, N_NODES * sizeof(int), hipMemcpyDeviceToDevice, stream);
    fill_kernel<<<(N_EDGES + 255) / 256, 256, 0, stream>>>(src, dst, cursor, edge_src);

    const int layer_grid = N_NODES / 4;  // 12500, exact

    // ---- layer 1 ----
    gin_layer3_kernel<<<layer_grid, 256, 0, stream>>>(x, row_start, edge_src,
        cw1[0], cb1[0], cg[0], cbb[0], cm[0], cv[0], cw2[0], cb2[0], h1);
    // ---- layer 2 ----
    gin_layer64_kernel<<<layer_grid, 256, 0, stream>>>(h1, row_start, edge_src,
        cw1[1], cb1[1], cg[1], cbb[1], cm[1], cv[1], cw2[1], cb2[1], h2);
    // ---- layer 3 ----
    gin_layer64_kernel<<<layer_grid, 256, 0, stream>>>(h2, row_start, edge_src,
        cw1[2], cb1[2], cg[2], cbb[2], cm[2], cv[2], cw2[2], cb2[2], h3);
    // ---- pool + head ----
    pool_head_kernel<<<G_GRAPHS, 3 * H, 0, stream>>>(h1, h2, h3, batch,
        lin1_w, lin1_b, lin2_w, lin2_b, out);
}

// Round 3
// 458.062 us; speedup vs baseline: 7.4449x; 1.4518x over previous
//
#include <hip/hip_runtime.h>
#include <hip/hip_bf16.h>
#include <math.h>

#define N_NODES 50000
#define N_EDGES 1600000
#define H 64
#define G_GRAPHS 512
#define C_CLS 2
#define BN_EPS 1e-5f

#define SCAN_CHUNK 1024            // elements per scan block (256 thr x 4)
#define SCAN_BLOCKS ((N_NODES + SCAN_CHUNK - 1) / SCAN_CHUNK)   // 49

// ---------- CSR build: histogram of dst + per-edge rank ----------
__global__ void hist_kernel(const int* __restrict__ dst, int* __restrict__ count,
                            int* __restrict__ rank) {
    int e = blockIdx.x * blockDim.x + threadIdx.x;
    if (e < N_EDGES) rank[e] = atomicAdd(&count[dst[e]], 1);
}

// ---------- scan pass 1: per-block sums ----------
__global__ __launch_bounds__(256) void scan_sums_kernel(const int* __restrict__ count,
                                                        int* __restrict__ block_sums) {
    __shared__ int s[256];
    int base = blockIdx.x * SCAN_CHUNK + threadIdx.x * 4;
    int sum = 0;
#pragma unroll
    for (int i = 0; i < 4; i++) {
        int idx = base + i;
        if (idx < N_NODES) sum += count[idx];
    }
    s[threadIdx.x] = sum;
    __syncthreads();
    for (int off = 128; off > 0; off >>= 1) {
        if (threadIdx.x < off) s[threadIdx.x] += s[threadIdx.x + off];
        __syncthreads();
    }
    if (threadIdx.x == 0) block_sums[blockIdx.x] = s[0];
}

// ---------- scan pass 2: exclusive scan of block sums (small) ----------
__global__ void scan_offsets_kernel(int* __restrict__ block_sums, int* __restrict__ row_start) {
    if (threadIdx.x == 0 && blockIdx.x == 0) {
        int acc = 0;
        for (int i = 0; i < SCAN_BLOCKS; i++) {
            int v = block_sums[i];
            block_sums[i] = acc;
            acc += v;
        }
        row_start[N_NODES] = N_EDGES;
    }
}

// ---------- scan pass 3: per-block exclusive scan ----------
__global__ __launch_bounds__(256) void scan_final_kernel(const int* __restrict__ count,
                                                         const int* __restrict__ block_sums,
                                                         int* __restrict__ row_start) {
    __shared__ int s[256];
    int base = blockIdx.x * SCAN_CHUNK + threadIdx.x * 4;
    int c[4], local[4];
    int sum = 0;
#pragma unroll
    for (int i = 0; i < 4; i++) {
        int idx = base + i;
        c[i] = (idx < N_NODES) ? count[idx] : 0;
        local[i] = sum;
        sum += c[i];
    }
    s[threadIdx.x] = sum;
    __syncthreads();
    for (int off = 1; off < 256; off <<= 1) {
        int v = 0;
        if (threadIdx.x >= off) v = s[threadIdx.x - off];
        __syncthreads();
        if (threadIdx.x >= off) s[threadIdx.x] += v;
        __syncthreads();
    }
    int tprefix = s[threadIdx.x] - sum;
    int boff = block_sums[blockIdx.x];
#pragma unroll
    for (int i = 0; i < 4; i++) {
        int idx = base + i;
        if (idx < N_NODES) row_start[idx] = boff + tprefix + local[i];
    }
}

// ---------- CSR fill (atomic-free: uses precomputed rank) ----------
__global__ void fill_kernel(const int* __restrict__ src, const int* __restrict__ dst,
                            const int* __restrict__ rank, const int* __restrict__ row_start,
                            int* __restrict__ edge_src) {
    int e = blockIdx.x * blockDim.x + threadIdx.x;
    if (e >= N_EDGES) return;
    edge_src[row_start[dst[e]] + rank[e]] = src[e];
}

// ---------- layer 1: gather(din=3) + MLP, one wave per node, bf16 out ----------
__global__ __launch_bounds__(256) void gin_layer3_kernel(
    const float* __restrict__ x, const int* __restrict__ row_start,
    const int* __restrict__ edge_src,
    const float* __restrict__ w1, const float* __restrict__ b1,
    const float* __restrict__ bn_g, const float* __restrict__ bn_b,
    const float* __restrict__ bn_m, const float* __restrict__ bn_v,
    const float* __restrict__ w2, const float* __restrict__ b2,
    __hip_bfloat16* __restrict__ hout) {
    __shared__ float s_w1[3 * H];
    __shared__ float s_w2[H * H];
    __shared__ float s_mid[4][H];
    __shared__ float s_scale[H], s_shift[H], s_b1[H], s_b2[H];

    int tid = threadIdx.x;
    for (int i = tid; i < 3 * H; i += 256) s_w1[i] = w1[i];
    for (int i = tid; i < H * H; i += 256) s_w2[i] = w2[i];
    if (tid < H) {
        float sc = rsqrtf(bn_v[tid] + BN_EPS) * bn_g[tid];
        s_scale[tid] = sc;
        s_shift[tid] = bn_b[tid] - bn_m[tid] * sc;
        s_b1[tid] = b1[tid];
        s_b2[tid] = b2[tid];
    }
    __syncthreads();

    int wave = tid >> 6;
    int j = tid & 63;
    int node = blockIdx.x * 4 + wave;

    int rs = row_start[node], re = row_start[node + 1];
    float a0 = 0.f, a1 = 0.f, a2 = 0.f;
    for (int t = rs + j; t < re; t += 64) {
        int s = edge_src[t];
        a0 += x[s * 3 + 0];
        a1 += x[s * 3 + 1];
        a2 += x[s * 3 + 2];
    }
#pragma unroll
    for (int off = 32; off > 0; off >>= 1) {
        a0 += __shfl_xor(a0, off);
        a1 += __shfl_xor(a1, off);
        a2 += __shfl_xor(a2, off);
    }
    float in0 = a0 + x[node * 3 + 0];
    float in1 = a1 + x[node * 3 + 1];
    float in2 = a2 + x[node * 3 + 2];

    float m = s_b1[j] + in0 * s_w1[0 * H + j] + in1 * s_w1[1 * H + j] + in2 * s_w1[2 * H + j];
    m = m * s_scale[j] + s_shift[j];
    m = fmaxf(m, 0.f);
    s_mid[wave][j] = m;
    __syncthreads();
    float o = s_b2[j];
#pragma unroll
    for (int k = 0; k < H; k++) o += s_mid[wave][k] * s_w2[k * H + j];
    o = fmaxf(o, 0.f);
    hout[(size_t)node * H + j] = __float2bfloat16(o);
}

// ---------- layers 2/3: gather(din=64, bf16) + MLP, one wave per node ----------
// 512 threads = 8 waves = 8 nodes/block; LDS ~38 KB -> 4 blocks/CU -> 32 waves/CU
__global__ __launch_bounds__(512) void gin_layer64_kernel(
    const __hip_bfloat16* __restrict__ hin, const int* __restrict__ row_start,
    const int* __restrict__ edge_src,
    const float* __restrict__ w1, const float* __restrict__ b1,
    const float* __restrict__ bn_g, const float* __restrict__ bn_b,
    const float* __restrict__ bn_m, const float* __restrict__ bn_v,
    const float* __restrict__ w2, const float* __restrict__ b2,
    __hip_bfloat16* __restrict__ hout) {
    __shared__ float s_w1[H * H];
    __shared__ float s_w2[H * H];
    __shared__ float s_in[8][H];
    __shared__ float s_mid[8][H];
    __shared__ float s_scale[H], s_shift[H], s_b1[H], s_b2[H];

    int tid = threadIdx.x;
    for (int i = tid; i < H * H; i += 512) { s_w1[i] = w1[i]; s_w2[i] = w2[i]; }
    if (tid < H) {
        float sc = rsqrtf(bn_v[tid] + BN_EPS) * bn_g[tid];
        s_scale[tid] = sc;
        s_shift[tid] = bn_b[tid] - bn_m[tid] * sc;
        s_b1[tid] = b1[tid];
        s_b2[tid] = b2[tid];
    }
    __syncthreads();

    int wave = tid >> 6;
    int j = tid & 63;
    int node = blockIdx.x * 8 + wave;   // grid covers exactly N

    int rs = row_start[node], re = row_start[node + 1];
    float a0 = 0.f, a1 = 0.f, a2 = 0.f, a3 = 0.f;
    for (int base = rs; base < re; base += 64) {
        int idx = base + j;
        int sv = (idx < re) ? edge_src[idx] : 0;   // coalesced chunk of edge ids
        int cnt = min(64, re - base);
        int i = 0;
        for (; i + 4 <= cnt; i += 4) {
            int s0 = __shfl(sv, i);
            int s1 = __shfl(sv, i + 1);
            int s2 = __shfl(sv, i + 2);
            int s3 = __shfl(sv, i + 3);
            a0 += __bfloat162float(hin[(size_t)s0 * H + j]);
            a1 += __bfloat162float(hin[(size_t)s1 * H + j]);
            a2 += __bfloat162float(hin[(size_t)s2 * H + j]);
            a3 += __bfloat162float(hin[(size_t)s3 * H + j]);
        }
        for (; i < cnt; i++) {
            int s = __shfl(sv, i);
            a0 += __bfloat162float(hin[(size_t)s * H + j]);
        }
    }
    float in = (a0 + a1) + (a2 + a3) + __bfloat162float(hin[(size_t)node * H + j]);
    s_in[wave][j] = in;
    __syncthreads();

    float m = s_b1[j];
#pragma unroll
    for (int k = 0; k < H; k++) m += s_in[wave][k] * s_w1[k * H + j];
    m = m * s_scale[j] + s_shift[j];
    m = fmaxf(m, 0.f);
    s_mid[wave][j] = m;
    __syncthreads();

    float o = s_b2[j];
#pragma unroll
    for (int k = 0; k < H; k++) o += s_mid[wave][k] * s_w2[k * H + j];
    o = fmaxf(o, 0.f);
    hout[(size_t)node * H + j] = __float2bfloat16(o);
}

// ---------- pool (batch sorted -> range per graph) + head ----------
__global__ __launch_bounds__(192) void pool_head_kernel(
    const __hip_bfloat16* __restrict__ h1, const __hip_bfloat16* __restrict__ h2,
    const __hip_bfloat16* __restrict__ h3, const int* __restrict__ batch,
    const float* __restrict__ lin1_w, const float* __restrict__ lin1_b,
    const float* __restrict__ lin2_w, const float* __restrict__ lin2_b,
    float* __restrict__ out) {
    __shared__ float s_row[3 * H];
    __shared__ float s_mid[3 * H];
    __shared__ float s_z[C_CLS];
    __shared__ int s_se[2];

    int g = blockIdx.x;
    int j = threadIdx.x;
    if (j < 2) {
        int target = g + j;
        int lo = 0, hi = N_NODES;
        while (lo < hi) {
            int mid = (lo + hi) >> 1;
            if (batch[mid] < target) lo = mid + 1; else hi = mid;
        }
        s_se[j] = lo;
    }
    __syncthreads();
    int ns = s_se[0], ne = s_se[1];

    int which = j >> 6;       // 0,1,2
    int f = j & 63;
    const __hip_bfloat16* h = (which == 0) ? h1 : ((which == 1) ? h2 : h3);
    float p = 0.f;
    for (int n = ns; n < ne; n++) p += __bfloat162float(h[(size_t)n * H + f]);
    s_row[j] = p;
    __syncthreads();

    float acc = lin1_b[j];
    for (int k = 0; k < 3 * H; k++) acc += s_row[k] * lin1_w[k * (3 * H) + j];
    s_mid[j] = fmaxf(acc, 0.f);
    __syncthreads();

    if (j < C_CLS) {
        float z = lin2_b[j];
        for (int k = 0; k < 3 * H; k++) z += s_mid[k] * lin2_w[k * C_CLS + j];
        s_z[j] = z;
    }
    __syncthreads();
    if (j < C_CLS) {
        float z0 = s_z[0], z1 = s_z[1];
        float mx = fmaxf(z0, z1);
        float lse = mx + logf(expf(z0 - mx) + expf(z1 - mx));
        out[g * C_CLS + j] = s_z[j];
        out[G_GRAPHS * C_CLS + g * C_CLS + j] = s_z[j] - lse;
    }
}

extern "C" void kernel_launch(void* const* d_in, const int* in_sizes, int n_in,
                              void* d_out, int out_size, void* d_ws, size_t ws_size,
                              hipStream_t stream) {
    const float* x = (const float*)d_in[0];
    const float* cw1[3], *cb1[3], *cg[3], *cbb[3], *cm[3], *cv[3], *cw2[3], *cb2[3];
    for (int l = 0; l < 3; l++) {
        int b = 1 + 8 * l;
        cw1[l] = (const float*)d_in[b + 0];
        cb1[l] = (const float*)d_in[b + 1];
        cg[l]  = (const float*)d_in[b + 2];
        cbb[l] = (const float*)d_in[b + 3];
        cm[l]  = (const float*)d_in[b + 4];
        cv[l]  = (const float*)d_in[b + 5];
        cw2[l] = (const float*)d_in[b + 6];
        cb2[l] = (const float*)d_in[b + 7];
    }
    const float* lin1_w = (const float*)d_in[25];
    const float* lin1_b = (const float*)d_in[26];
    const float* lin2_w = (const float*)d_in[27];
    const float* lin2_b = (const float*)d_in[28];
    const int* edge_index = (const int*)d_in[29];
    const int* batch = (const int*)d_in[30];
    const int* src = edge_index;
    const int* dst = edge_index + N_EDGES;
    float* out = (float*)d_out;

    // workspace layout (all 4-byte aligned)
    int* edge_src = (int*)d_ws;                     // E
    int* rank = edge_src + N_EDGES;                 // E
    int* count = rank + N_EDGES;                    // N
    int* row_start = count + N_NODES;               // N+1
    int* block_sums = row_start + N_NODES + 1;      // SCAN_BLOCKS
    __hip_bfloat16* h1 = (__hip_bfloat16*)(block_sums + SCAN_BLOCKS + 1);  // N*H
    __hip_bfloat16* h2 = h1 + (size_t)N_NODES * H;
    __hip_bfloat16* h3 = h2 + (size_t)N_NODES * H;

    // ---- build CSR (dst -> list of src) ----
    hipMemsetAsync(count, 0, N_NODES * sizeof(int), stream);
    hist_kernel<<<(N_EDGES + 255) / 256, 256, 0, stream>>>(dst, count, rank);
    scan_sums_kernel<<<SCAN_BLOCKS, 256, 0, stream>>>(count, block_sums);
    scan_offsets_kernel<<<1, 64, 0, stream>>>(block_sums, row_start);
    scan_final_kernel<<<SCAN_BLOCKS, 256, 0, stream>>>(count, block_sums, row_start);
    fill_kernel<<<(N_EDGES + 255) / 256, 256, 0, stream>>>(src, dst, rank, row_start, edge_src);

    // ---- layer 1 ----
    gin_layer3_kernel<<<N_NODES / 4, 256, 0, stream>>>(x, row_start, edge_src,
        cw1[0], cb1[0], cg[0], cbb[0], cm[0], cv[0], cw2[0], cb2[0], h1);
    // ---- layer 2 ----
    gin_layer64_kernel<<<N_NODES / 8, 512, 0, stream>>>(h1, row_start, edge_src,
        cw1[1], cb1[1], cg[1], cbb[1], cm[1], cv[1], cw2[1], cb2[1], h2);
    // ---- layer 3 ----
    gin_layer64_kernel<<<N_NODES / 8, 512, 0, stream>>>(h2, row_start, edge_src,
        cw1[2], cb1[2], cg[2], cbb[2], cm[2], cv[2], cw2[2], cb2[2], h3);
    // ---- pool + head ----
    pool_head_kernel<<<G_GRAPHS, 3 * H, 0, stream>>>(h1, h2, h3, batch,
        lin1_w, lin1_b, lin2_w, lin2_b, out);
}